// Round 10
// baseline (1142.637 us; speedup 1.0000x reference)
//
#include <hip/hip_runtime.h>
#include <hip/hip_bf16.h>
#include <math.h>

typedef __hip_bfloat16 bf16;

#define NQ      16384
#define CDIM    256
#define NHEADS  8
#define NPOINTS 4
#define NCAM    6
#define HF      58
#define WF      100
#define HWF     (HF*WF)        /* 5800 */
#define NFEAT   (NCAM*HWF)     /* 34800 */
#define HD      32
#define NLAYERS 6

typedef __attribute__((ext_vector_type(8))) short short8;
typedef __attribute__((ext_vector_type(4))) float floatx4;

__device__ __forceinline__ float toF(float x) { return x; }
__device__ __forceinline__ float toF(bf16 x) { return __bfloat162float(x); }
__device__ __forceinline__ void storeD(float* p, float v) { *p = v; }
__device__ __forceinline__ void storeD(bf16* p, float v) { *p = __float2bfloat16(v); }

__device__ __forceinline__ float bfLo(unsigned u) { return __uint_as_float(u << 16); }
__device__ __forceinline__ float bfHi(unsigned u) { return __uint_as_float(u & 0xffff0000u); }

// ---------------------------------------------------------------------------
// MFMA bf16 GEMM: D[M,N] = A[M,K] * BT[N,K]^T + bias[N]  (optional ReLU)
// 128x128 tile, BK=32, 4 waves 2x2. Batched over blockIdx.z via strides.
// bf16 D: two-phase LDS-staged coalesced epilogue (LDS stays 20.5 KB).
// ---------------------------------------------------------------------------
template <bool RELU>
__global__ __launch_bounds__(256) void gemm_mfma(
    const bf16* __restrict__ A, const bf16* __restrict__ BT,
    const float* __restrict__ bias, bf16* __restrict__ D,
    int M, int N, int K, size_t sB, size_t sBias, size_t sD)
{
    int z = blockIdx.z;
    BT += (size_t)z * sB;
    bias += (size_t)z * sBias;
    D += (size_t)z * sD;

    __shared__ bf16 smem[128 * 80];
    bf16* As = smem;
    bf16* Bs = smem + 128 * 40;

    int tid = threadIdx.x;
    int lane = tid & 63, w = tid >> 6;
    int wm = w & 1, wn = w >> 1;
    int l15 = lane & 15, quad = lane >> 4;
    int bm = blockIdx.y * 128, bn = blockIdx.x * 128;

    floatx4 acc[4][4];
#pragma unroll
    for (int i = 0; i < 4; i++)
#pragma unroll
        for (int j = 0; j < 4; j++)
            acc[i][j] = (floatx4){0.f, 0.f, 0.f, 0.f};

    int srow = tid >> 2;
    int skc  = (tid & 3) * 8;

    for (int k0 = 0; k0 < K; k0 += 32) {
#pragma unroll
        for (int r = 0; r < 2; r++) {
            int row = srow + r * 64;
            int gm = bm + row;
            int4 va = {0, 0, 0, 0};
            if (gm < M) va = *(const int4*)(A + (size_t)gm * K + k0 + skc);
            *(int4*)(&As[row * 40 + skc]) = va;
            int gn = bn + row;
            int4 vb = *(const int4*)(BT + (size_t)gn * K + k0 + skc);
            *(int4*)(&Bs[row * 40 + skc]) = vb;
        }
        __syncthreads();

        short8 a[4], b[4];
#pragma unroll
        for (int i = 0; i < 4; i++)
            a[i] = *(const short8*)(&As[(wm * 64 + i * 16 + l15) * 40 + quad * 8]);
#pragma unroll
        for (int j = 0; j < 4; j++)
            b[j] = *(const short8*)(&Bs[(wn * 64 + j * 16 + l15) * 40 + quad * 8]);
#pragma unroll
        for (int i = 0; i < 4; i++)
#pragma unroll
            for (int j = 0; j < 4; j++)
                acc[i][j] = __builtin_amdgcn_mfma_f32_16x16x32_bf16(
                    a[i], b[j], acc[i][j], 0, 0, 0);
        __syncthreads();
    }

    // two-phase staged epilogue: 64 rows at a time in 64x136 LDS tile
#pragma unroll
    for (int ph = 0; ph < 2; ph++) {
        if (wm == ph) {
#pragma unroll
            for (int i = 0; i < 4; i++) {
#pragma unroll
                for (int j = 0; j < 4; j++) {
                    int col = wn * 64 + j * 16 + l15;
                    float bv = bias[bn + col];
#pragma unroll
                    for (int r = 0; r < 4; r++) {
                        int row = i * 16 + quad * 4 + r;   // 0..63 within phase
                        float v = acc[i][j][r] + bv;
                        if (RELU) v = fmaxf(v, 0.f);
                        smem[row * 136 + col] = __float2bfloat16(v);
                    }
                }
            }
        }
        __syncthreads();
        int lr0 = tid >> 4;
        int ck  = tid & 15;
#pragma unroll
        for (int pass = 0; pass < 4; pass++) {
            int lr = pass * 16 + lr0;
            int gm = bm + ph * 64 + lr;
            if (gm < M) {
                uint4 v = *(const uint4*)(&smem[lr * 136 + ck * 8]);
                *(uint4*)(D + (size_t)gm * N + bn + ck * 8) = v;
            }
        }
        __syncthreads();
    }
}

// ---------------------------------------------------------------------------
// TSA in-loop GEMM: A = qb (M = NQ), packed BT (384 rows x K=256):
//   rows 0..255   = tsa_vw^T  -> vcur (bf16 row-major, staged)
//   rows 256..383 = [ow|aw|0] -> offlog (fp32)
// grid (3, 128): bn3 = 0,1 -> vcur columns; bn3 = 2 -> offlog.
// ---------------------------------------------------------------------------
__global__ __launch_bounds__(256) void gemm_tsa(
    const bf16* __restrict__ A, const bf16* __restrict__ BT,
    const float* __restrict__ bias,
    bf16* __restrict__ vcur, float* __restrict__ offlog)
{
    int bn3 = blockIdx.x;
    int bm = blockIdx.y * 128;
    int bn = bn3 * 128;

    __shared__ bf16 smem[128 * 80];
    bf16* As = smem;
    bf16* Bs = smem + 128 * 40;

    int tid = threadIdx.x;
    int lane = tid & 63, w = tid >> 6;
    int wm = w & 1, wn = w >> 1;
    int l15 = lane & 15, quad = lane >> 4;

    floatx4 acc[4][4];
#pragma unroll
    for (int i = 0; i < 4; i++)
#pragma unroll
        for (int j = 0; j < 4; j++)
            acc[i][j] = (floatx4){0.f, 0.f, 0.f, 0.f};

    int srow = tid >> 2;
    int skc  = (tid & 3) * 8;

    for (int k0 = 0; k0 < 256; k0 += 32) {
#pragma unroll
        for (int r = 0; r < 2; r++) {
            int row = srow + r * 64;
            *(int4*)(&As[row * 40 + skc]) =
                *(const int4*)(A + (size_t)(bm + row) * 256 + k0 + skc);
            *(int4*)(&Bs[row * 40 + skc]) =
                *(const int4*)(BT + (size_t)(bn + row) * 256 + k0 + skc);
        }
        __syncthreads();

        short8 a[4], b[4];
#pragma unroll
        for (int i = 0; i < 4; i++)
            a[i] = *(const short8*)(&As[(wm * 64 + i * 16 + l15) * 40 + quad * 8]);
#pragma unroll
        for (int j = 0; j < 4; j++)
            b[j] = *(const short8*)(&Bs[(wn * 64 + j * 16 + l15) * 40 + quad * 8]);
#pragma unroll
        for (int i = 0; i < 4; i++)
#pragma unroll
            for (int j = 0; j < 4; j++)
                acc[i][j] = __builtin_amdgcn_mfma_f32_16x16x32_bf16(
                    a[i], b[j], acc[i][j], 0, 0, 0);
        __syncthreads();
    }

    if (bn3 < 2) {
#pragma unroll
        for (int ph = 0; ph < 2; ph++) {
            if (wm == ph) {
#pragma unroll
                for (int i = 0; i < 4; i++) {
#pragma unroll
                    for (int j = 0; j < 4; j++) {
                        int col = wn * 64 + j * 16 + l15;
                        float bv = bias[bn + col];
#pragma unroll
                        for (int r = 0; r < 4; r++) {
                            int row = i * 16 + quad * 4 + r;
                            smem[row * 136 + col] = __float2bfloat16(acc[i][j][r] + bv);
                        }
                    }
                }
            }
            __syncthreads();
            int lr0 = tid >> 4;
            int ck  = tid & 15;
#pragma unroll
            for (int pass = 0; pass < 4; pass++) {
                int lr = pass * 16 + lr0;
                int gm = bm + ph * 64 + lr;
                uint4 v = *(const uint4*)(&smem[lr * 136 + ck * 8]);
                *(uint4*)(vcur + (size_t)gm * 256 + bn + ck * 8) = v;
            }
            __syncthreads();
        }
    } else {
#pragma unroll
        for (int i = 0; i < 4; i++) {
#pragma unroll
            for (int j = 0; j < 4; j++) {
                int col = wn * 64 + j * 16 + l15;       // 0..127
                float bv = bias[256 + col];
#pragma unroll
                for (int r = 0; r < 4; r++) {
                    int row = bm + wm * 64 + i * 16 + quad * 4 + r;
                    offlog[(size_t)row * 128 + col] = acc[i][j][r] + bv;
                }
            }
        }
    }
}

// ---------------------------------------------------------------------------
// Fused GEMM + residual + LayerNorm (N = 256, M mult of 64):
//   t = A*BT^T + bias ; x = q + t ; q = LN(x)*g + b ; qb = bf16(q)
// OFF=true: additionally offlog = bf16(q) @ sowT^T + sob  (fused SCA off/attn)
// ---------------------------------------------------------------------------
template <bool OFF>
__global__ __launch_bounds__(512) void gemm_ln(
    const bf16* __restrict__ A, const bf16* __restrict__ BT,
    const float* __restrict__ bias,
    float* __restrict__ qv, bf16* __restrict__ qb,
    const float* __restrict__ g, const float* __restrict__ b,
    int K,
    const bf16* __restrict__ sow, const float* __restrict__ sob,
    float* __restrict__ offlog)
{
    constexpr int SMN = OFF ? 64 * 272 : (64 * 40 + 256 * 40);
    __shared__ bf16 smem[SMN];
    __shared__ float red[2][64][4];
    __shared__ float stats[2][64];
    bf16* As = smem;
    bf16* Bs = smem + 64 * 40;

    int tid = threadIdx.x;
    int lane = tid & 63, w = tid >> 6;
    int wm = w & 1, wn = w >> 1;              // 2 x 4
    int l15 = lane & 15, quad = lane >> 4;
    int bm = blockIdx.x * 64;

    floatx4 acc[2][4];
#pragma unroll
    for (int i = 0; i < 2; i++)
#pragma unroll
        for (int j = 0; j < 4; j++)
            acc[i][j] = (floatx4){0.f, 0.f, 0.f, 0.f};

    int srow = tid >> 2;
    int skc  = (tid & 3) * 8;

    for (int k0 = 0; k0 < K; k0 += 32) {
        *(int4*)(&Bs[srow * 40 + skc]) =
            *(const int4*)(BT + (size_t)srow * K + k0 + skc);
        *(int4*)(&Bs[(srow + 128) * 40 + skc]) =
            *(const int4*)(BT + (size_t)(srow + 128) * K + k0 + skc);
        if (tid < 256)
            *(int4*)(&As[(tid >> 2) * 40 + skc]) =
                *(const int4*)(A + (size_t)(bm + (tid >> 2)) * K + k0 + skc);
        __syncthreads();

        short8 a[2], bfr[4];
#pragma unroll
        for (int i = 0; i < 2; i++)
            a[i] = *(const short8*)(&As[(wm * 32 + i * 16 + l15) * 40 + quad * 8]);
#pragma unroll
        for (int j = 0; j < 4; j++)
            bfr[j] = *(const short8*)(&Bs[(wn * 64 + j * 16 + l15) * 40 + quad * 8]);
#pragma unroll
        for (int i = 0; i < 2; i++)
#pragma unroll
            for (int j = 0; j < 4; j++)
                acc[i][j] = __builtin_amdgcn_mfma_f32_16x16x32_bf16(
                    a[i], bfr[j], acc[i][j], 0, 0, 0);
        __syncthreads();
    }

    float x[2][4][4];
#pragma unroll
    for (int i = 0; i < 2; i++) {
#pragma unroll
        for (int j = 0; j < 4; j++) {
            int col = wn * 64 + j * 16 + l15;
            float bv = bias[col];
#pragma unroll
            for (int r = 0; r < 4; r++) {
                int row = bm + wm * 32 + i * 16 + quad * 4 + r;
                x[i][j][r] = qv[(size_t)row * CDIM + col] + acc[i][j][r] + bv;
            }
        }
    }
#pragma unroll
    for (int i = 0; i < 2; i++) {
#pragma unroll
        for (int r = 0; r < 4; r++) {
            float s = x[i][0][r] + x[i][1][r] + x[i][2][r] + x[i][3][r];
            float sq = x[i][0][r] * x[i][0][r] + x[i][1][r] * x[i][1][r] +
                       x[i][2][r] * x[i][2][r] + x[i][3][r] * x[i][3][r];
#pragma unroll
            for (int m = 1; m < 16; m <<= 1) {
                s += __shfl_xor(s, m);
                sq += __shfl_xor(sq, m);
            }
            if (l15 == 0) {
                int rl = wm * 32 + i * 16 + quad * 4 + r;
                red[0][rl][wn] = s;
                red[1][rl][wn] = sq;
            }
        }
    }
    __syncthreads();
    if (tid < 64) {
        float s = red[0][tid][0] + red[0][tid][1] + red[0][tid][2] + red[0][tid][3];
        float sq = red[1][tid][0] + red[1][tid][1] + red[1][tid][2] + red[1][tid][3];
        float mean = s * (1.f / CDIM);
        float var = fmaxf(sq * (1.f / CDIM) - mean * mean, 0.f);
        stats[0][tid] = mean;
        stats[1][tid] = rsqrtf(var + 1e-5f);
    }
    __syncthreads();
#pragma unroll
    for (int i = 0; i < 2; i++) {
#pragma unroll
        for (int j = 0; j < 4; j++) {
            int col = wn * 64 + j * 16 + l15;
            float gc = g[col], bc = b[col];
#pragma unroll
            for (int r = 0; r < 4; r++) {
                int rl = wm * 32 + i * 16 + quad * 4 + r;
                int row = bm + rl;
                float y = (x[i][j][r] - stats[0][rl]) * stats[1][rl] * gc + bc;
                qv[(size_t)row * CDIM + col] = y;
                bf16 yb = __float2bfloat16(y);
                qb[(size_t)row * CDIM + col] = yb;
                if (OFF) smem[rl * 272 + col] = yb;   // stage for offlog MFMA
            }
        }
    }

    if (OFF) {
        __syncthreads();
        // offlog[bm.., 0..127] = y_bf16 @ sow^T + sob   (M=64,N=128,K=256)
        floatx4 a2[2][2];
#pragma unroll
        for (int i = 0; i < 2; i++)
#pragma unroll
            for (int j = 0; j < 2; j++)
                a2[i][j] = (floatx4){0.f, 0.f, 0.f, 0.f};
        for (int k0 = 0; k0 < 256; k0 += 32) {
            short8 af[2], bf2[2];
#pragma unroll
            for (int i = 0; i < 2; i++)
                af[i] = *(const short8*)(&smem[(wm * 32 + i * 16 + l15) * 272 + k0 + quad * 8]);
#pragma unroll
            for (int j = 0; j < 2; j++)
                bf2[j] = *(const short8*)(sow + (size_t)(wn * 32 + j * 16 + l15) * 256 + k0 + quad * 8);
#pragma unroll
            for (int i = 0; i < 2; i++)
#pragma unroll
                for (int j = 0; j < 2; j++)
                    a2[i][j] = __builtin_amdgcn_mfma_f32_16x16x32_bf16(
                        af[i], bf2[j], a2[i][j], 0, 0, 0);
        }
#pragma unroll
        for (int i = 0; i < 2; i++) {
#pragma unroll
            for (int j = 0; j < 2; j++) {
                int col = wn * 32 + j * 16 + l15;
                float bv = sob[col];
#pragma unroll
                for (int r = 0; r < 4; r++) {
                    int row = bm + wm * 32 + i * 16 + quad * 4 + r;
                    offlog[(size_t)row * 128 + col] = a2[i][j][r] + bv;
                }
            }
        }
    }
}

// ---------------------------------------------------------------------------
// Weight convert+transpose, batched over layers (blockIdx.z)
// ---------------------------------------------------------------------------
__global__ void wt_cvt_kernel(const float* __restrict__ W, bf16* __restrict__ WT,
                              int K, int N)
{
    __shared__ float tile[32][33];
    int l = blockIdx.z;
    const float* Wl = W + (size_t)l * K * N;
    bf16* WTl = WT + (size_t)l * K * N;
    int k0 = blockIdx.x * 32, n0 = blockIdx.y * 32;
    int tx = threadIdx.x, ty = threadIdx.y;
    for (int i = 0; i < 32; i += 8)
        tile[ty + i][tx] = Wl[(size_t)(k0 + ty + i) * N + n0 + tx];
    __syncthreads();
    for (int i = 0; i < 32; i += 8)
        WTl[(size_t)(n0 + ty + i) * K + k0 + tx] = __float2bfloat16(tile[tx][ty + i]);
}

// Pack TSA fused weights: 384 rows = [vw^T(256) | ow(64) | aw(32) | 0(32)]
__global__ void pack_tsa_kernel(const float* __restrict__ vw, const float* __restrict__ vb,
                                const float* __restrict__ ow, const float* __restrict__ ob,
                                const float* __restrict__ aw, const float* __restrict__ ab,
                                bf16* __restrict__ WT, float* __restrict__ BIAS)
{
    int n = blockIdx.x;
    int l = blockIdx.y;
    int k = threadIdx.x;
    float v = 0.f;
    if (n < 256)      v = vw[((size_t)l * 256 + k) * 256 + n];
    else if (n < 320) v = ow[((size_t)l * 256 + k) * 64 + (n - 256)];
    else if (n < 352) v = aw[((size_t)l * 256 + k) * 32 + (n - 320)];
    WT[((size_t)l * 384 + n) * 256 + k] = __float2bfloat16(v);
    if (k == 0) {
        float bv = 0.f;
        if (n < 256)      bv = vb[l * 256 + n];
        else if (n < 320) bv = ob[l * 64 + (n - 256)];
        else if (n < 352) bv = ab[l * 32 + (n - 320)];
        BIAS[l * 384 + n] = bv;
    }
}

__global__ void pack_offattn_kernel(const float* __restrict__ ow, const float* __restrict__ ob,
                                    const float* __restrict__ aw, const float* __restrict__ ab,
                                    bf16* __restrict__ WT, float* __restrict__ BIAS)
{
    int l = blockIdx.y;
    int n = blockIdx.x;
    int k = threadIdx.x;
    float v = 0.f;
    if (n < 64)      v = ow[((size_t)l * 256 + k) * 64 + n];
    else if (n < 96) v = aw[((size_t)l * 256 + k) * 32 + (n - 64)];
    WT[((size_t)l * 128 + n) * 256 + k] = __float2bfloat16(v);
    if (k == 0) {
        float bv = 0.f;
        if (n < 64)      bv = ob[l * 64 + n];
        else if (n < 96) bv = ab[l * 32 + (n - 64)];
        BIAS[l * 128 + n] = bv;
    }
}

__global__ void feats_cvt_kernel(const float* __restrict__ in, bf16* __restrict__ outT)
{
    __shared__ float tile[32][33];
    int c = blockIdx.z;
    int r0 = blockIdx.x * 32, ch0 = blockIdx.y * 32;
    int tx = threadIdx.x, ty = threadIdx.y;
    for (int i = 0; i < 32; i += 8) {
        int r = r0 + tx, ch = ch0 + ty + i;
        tile[ty + i][tx] = (r < HWF) ? in[((size_t)c * CDIM + ch) * HWF + r] : 0.f;
    }
    __syncthreads();
    for (int i = 0; i < 32; i += 8) {
        int r = r0 + ty + i, ch = ch0 + tx;
        if (r < HWF)
            outT[((size_t)c * HWF + r) * CDIM + ch] = __float2bfloat16(tile[tx][ty + i]);
    }
}

__global__ __launch_bounds__(256) void cvt_bf16_kernel(const float* __restrict__ in,
                                                       bf16* __restrict__ out, int n)
{
    int i = blockIdx.x * 256 + threadIdx.x;
    if (i < n) out[i] = __float2bfloat16(in[i]);
}

__global__ __launch_bounds__(256) void init_q_kernel(const float* __restrict__ in,
                                                     float* __restrict__ q,
                                                     bf16* __restrict__ qb, int n)
{
    int i = blockIdx.x * 256 + threadIdx.x;
    if (i < n) { float v = in[i]; q[i] = v; qb[i] = __float2bfloat16(v); }
}

// ---------------------------------------------------------------------------
__global__ void invert4_kernel(const float* __restrict__ extr, float* __restrict__ ego)
{
    int c = threadIdx.x;
    if (c >= NCAM) return;
    float a[4][8];
    for (int i = 0; i < 4; i++)
        for (int j = 0; j < 4; j++) {
            a[i][j] = extr[c * 16 + i * 4 + j];
            a[i][4 + j] = (i == j) ? 1.f : 0.f;
        }
    for (int col = 0; col < 4; col++) {
        int piv = col;
        float best = fabsf(a[col][col]);
        for (int r = col + 1; r < 4; r++) {
            float v = fabsf(a[r][col]);
            if (v > best) { best = v; piv = r; }
        }
        if (piv != col)
            for (int j = 0; j < 8; j++) {
                float t = a[col][j]; a[col][j] = a[piv][j]; a[piv][j] = t;
            }
        float inv = 1.f / a[col][col];
        for (int j = 0; j < 8; j++) a[col][j] *= inv;
        for (int r = 0; r < 4; r++) {
            if (r == col) continue;
            float f = a[r][col];
            for (int j = 0; j < 8; j++) a[r][j] -= f * a[col][j];
        }
    }
    for (int i = 0; i < 4; i++)
        for (int j = 0; j < 4; j++)
            ego[c * 16 + i * 4 + j] = a[i][4 + j];
}

__global__ __launch_bounds__(256) void refcam_kernel(
    const float* __restrict__ ego, const float* __restrict__ intr,
    float* __restrict__ refcam, float* __restrict__ validb)
{
    int t = blockIdx.x * 256 + threadIdx.x;
    if (t >= NCAM * NQ * NPOINTS) return;
    int p = t & 3;
    int n = (t >> 2) & (NQ - 1);
    int c = t >> 16;

    float gx = ((n & 127) + 0.5f) / 128.0f;
    float gy = ((n >> 7) + 0.5f) / 128.0f;
    float xm = -51.2f + gx * 102.4f;
    float ym = -51.2f + gy * 102.4f;
    float zm = -5.0f + (p + 0.5f) * 2.0f;

    const float* E = ego + c * 16;
    float pc[3];
#pragma unroll
    for (int i = 0; i < 3; i++)
        pc[i] = E[i * 4 + 0] * xm + E[i * 4 + 1] * ym + E[i * 4 + 2] * zm + E[i * 4 + 3];

    const float* I = intr + c * 9;
    float im[3];
#pragma unroll
    for (int i = 0; i < 3; i++)
        im[i] = I[i * 3 + 0] * pc[0] + I[i * 3 + 1] * pc[1] + I[i * 3 + 2] * pc[2];

    float z = im[2];
    float zc = fmaxf(z, 1e-5f);
    float un = im[0] / (zc * (float)WF);
    float vn = im[1] / (zc * (float)HF);
    float val = (z > 1e-5f && un >= 0.f && un <= 1.f && vn >= 0.f && vn <= 1.f) ? 1.f : 0.f;

    size_t idx = ((size_t)c * NQ + n) * NPOINTS + p;
    refcam[idx * 2] = un;
    refcam[idx * 2 + 1] = vn;
    validb[idx] = val;
}

// ---------------------------------------------------------------------------
// TSA sampling: 2048 blocks (XCD-swizzled), 256 thr = 8 queries x 8 heads x
// 4 ch-octs; two 16B loads per tap (prev + cur).
// ---------------------------------------------------------------------------
__global__ __launch_bounds__(256) void tsa_sample_kernel(
    const bf16* __restrict__ vprev, const bf16* __restrict__ vcur,
    const float* __restrict__ offlog, bf16* __restrict__ outA)
{
    int blk = blockIdx.x;
    int qo = (blk & 7) * 256 + (blk >> 3);
    int t = threadIdx.x;
    int n = qo * 8 + (t >> 5);
    int r = t & 31;
    int h = r >> 2;
    int d8 = r & 3;
    int col = h * HD + d8 * 8;

    const float* fl = offlog + (size_t)n * 128;
    const float* lg = fl + 64 + h * 4;
    float l0 = lg[0], l1 = lg[1], l2 = lg[2], l3 = lg[3];
    float mx = fmaxf(fmaxf(l0, l1), fmaxf(l2, l3));
    float e0 = expf(l0 - mx), e1 = expf(l1 - mx), e2 = expf(l2 - mx), e3 = expf(l3 - mx);
    float inv = 1.f / (e0 + e1 + e2 + e3);
    float w[4] = { e0 * inv, e1 * inv, e2 * inv, e3 * inv };

    const float* of = fl + h * 8;
    float rx = ((n & 127) + 0.5f) / 128.f;
    float ry = ((n >> 7) + 0.5f) / 128.f;

    float a0 = 0.f, a1 = 0.f, a2 = 0.f, a3 = 0.f;
    float a4 = 0.f, a5 = 0.f, a6 = 0.f, a7 = 0.f;
#pragma unroll
    for (int p = 0; p < NPOINTS; p++) {
        float lx = rx + of[p * 2] * (1.f / 128.f);
        float ly = ry + of[p * 2 + 1] * (1.f / 128.f);
        float ix = lx * 128.f - 0.5f;
        float iy = ly * 128.f - 0.5f;
        float xf = floorf(ix), yf = floorf(iy);
        float fx = ix - xf, fy = iy - yf;
        int x0 = (int)xf, y0 = (int)yf;
#pragma unroll
        for (int dy = 0; dy < 2; dy++) {
            int yi = y0 + dy;
            if (yi < 0 || yi >= 128) continue;
            float wy = dy ? fy : 1.f - fy;
#pragma unroll
            for (int dx = 0; dx < 2; dx++) {
                int xi = x0 + dx;
                if (xi < 0 || xi >= 128) continue;
                float wgt = w[p] * wy * (dx ? fx : 1.f - fx);
                size_t pix = (size_t)(yi * 128 + xi) * CDIM + col;
                uint4 vp = *(const uint4*)(vprev + pix);
                uint4 vc = *(const uint4*)(vcur + pix);
                a0 += wgt * (bfLo(vp.x) + bfLo(vc.x));
                a1 += wgt * (bfHi(vp.x) + bfHi(vc.x));
                a2 += wgt * (bfLo(vp.y) + bfLo(vc.y));
                a3 += wgt * (bfHi(vp.y) + bfHi(vc.y));
                a4 += wgt * (bfLo(vp.z) + bfLo(vc.z));
                a5 += wgt * (bfHi(vp.z) + bfHi(vc.z));
                a6 += wgt * (bfLo(vp.w) + bfLo(vc.w));
                a7 += wgt * (bfHi(vp.w) + bfHi(vc.w));
            }
        }
    }
    union { bf16 b[8]; uint4 u; } pk;
    pk.b[0] = __float2bfloat16(0.5f * a0);
    pk.b[1] = __float2bfloat16(0.5f * a1);
    pk.b[2] = __float2bfloat16(0.5f * a2);
    pk.b[3] = __float2bfloat16(0.5f * a3);
    pk.b[4] = __float2bfloat16(0.5f * a4);
    pk.b[5] = __float2bfloat16(0.5f * a5);
    pk.b[6] = __float2bfloat16(0.5f * a6);
    pk.b[7] = __float2bfloat16(0.5f * a7);
    *(uint4*)(outA + (size_t)n * CDIM + col) = pk.u;
}

// ---------------------------------------------------------------------------
// SCA sampling: 2048 blocks (XCD-swizzled), 256 thr = 8 queries x 8 heads x
// 4 ch-octs; 16B loads. cnt computed inline.
// ---------------------------------------------------------------------------
__global__ __launch_bounds__(256) void sca_sample_kernel(
    const bf16* __restrict__ vimg, const float* __restrict__ offlog,
    const float* __restrict__ refcam, const float* __restrict__ validb,
    bf16* __restrict__ outA)
{
    int blk = blockIdx.x;
    int qo = (blk & 7) * 256 + (blk >> 3);
    int t = threadIdx.x;
    int n = qo * 8 + (t >> 5);
    int r = t & 31;
    int h = r >> 2;
    int d8 = r & 3;
    int col = h * HD + d8 * 8;

    const float* fl = offlog + (size_t)n * 128;
    const float* lg = fl + 64 + h * 4;
    float l0 = lg[0], l1 = lg[1], l2 = lg[2], l3 = lg[3];
    float mx = fmaxf(fmaxf(l0, l1), fmaxf(l2, l3));
    float e0 = expf(l0 - mx), e1 = expf(l1 - mx), e2 = expf(l2 - mx), e3 = expf(l3 - mx);
    float inv = 1.f / (e0 + e1 + e2 + e3);
    float w[4] = { e0 * inv, e1 * inv, e2 * inv, e3 * inv };

    const float* of = fl + h * 8;
    float ox[4], oy[4];
#pragma unroll
    for (int p = 0; p < NPOINTS; p++) {
        ox[p] = of[p * 2] * (1.f / (float)WF);
        oy[p] = of[p * 2 + 1] * (1.f / (float)HF);
    }

    float a0 = 0.f, a1 = 0.f, a2 = 0.f, a3 = 0.f;
    float a4 = 0.f, a5 = 0.f, a6 = 0.f, a7 = 0.f;
    float vsum = 0.f;
    for (int c = 0; c < NCAM; c++) {
        const bf16* vb = vimg + (size_t)c * HWF * CDIM;
        size_t base = ((size_t)c * NQ + n) * NPOINTS;
#pragma unroll
        for (int p = 0; p < NPOINTS; p++) {
            float vl = validb[base + p];
            vsum += vl;
            if (vl == 0.f) continue;
            float lx = refcam[(base + p) * 2] + ox[p];
            float ly = refcam[(base + p) * 2 + 1] + oy[p];
            float ix = lx * (float)WF - 0.5f;
            float iy = ly * (float)HF - 0.5f;
            float xf = floorf(ix), yf = floorf(iy);
            float fx = ix - xf, fy = iy - yf;
            int x0 = (int)xf, y0 = (int)yf;
            float wp_ = w[p] * vl;
#pragma unroll
            for (int dy = 0; dy < 2; dy++) {
                int yi = y0 + dy;
                if (yi < 0 || yi >= HF) continue;
                float wy = dy ? fy : 1.f - fy;
#pragma unroll
                for (int dx = 0; dx < 2; dx++) {
                    int xi = x0 + dx;
                    if (xi < 0 || xi >= WF) continue;
                    float wgt = wp_ * wy * (dx ? fx : 1.f - fx);
                    uint4 u = *(const uint4*)(vb + (size_t)(yi * WF + xi) * CDIM + col);
                    a0 += wgt * bfLo(u.x);
                    a1 += wgt * bfHi(u.x);
                    a2 += wgt * bfLo(u.y);
                    a3 += wgt * bfHi(u.y);
                    a4 += wgt * bfLo(u.z);
                    a5 += wgt * bfHi(u.z);
                    a6 += wgt * bfLo(u.w);
                    a7 += wgt * bfHi(u.w);
                }
            }
        }
    }
    float ic = 1.f / fmaxf(vsum, 1.f);
    union { bf16 b[8]; uint4 u; } pk;
    pk.b[0] = __float2bfloat16(a0 * ic);
    pk.b[1] = __float2bfloat16(a1 * ic);
    pk.b[2] = __float2bfloat16(a2 * ic);
    pk.b[3] = __float2bfloat16(a3 * ic);
    pk.b[4] = __float2bfloat16(a4 * ic);
    pk.b[5] = __float2bfloat16(a5 * ic);
    pk.b[6] = __float2bfloat16(a6 * ic);
    pk.b[7] = __float2bfloat16(a7 * ic);
    *(uint4*)(outA + (size_t)n * CDIM + col) = pk.u;
}

// ---------------------------------------------------------------------------
__global__ void out_transpose_kernel(const float* __restrict__ q, float* __restrict__ out)
{
    __shared__ float tile[32][33];
    int n0 = blockIdx.x * 32;
    int c0 = blockIdx.y * 32;
    int tx = threadIdx.x, ty = threadIdx.y;
    for (int i = 0; i < 32; i += 8)
        tile[ty + i][tx] = q[(size_t)(n0 + ty + i) * CDIM + c0 + tx];
    __syncthreads();
    for (int i = 0; i < 32; i += 8)
        out[(size_t)(c0 + ty + i) * NQ + n0 + tx] = tile[tx][ty + i];
}

// ---------------------------------------------------------------------------
// Host launcher
// ---------------------------------------------------------------------------
extern "C" void kernel_launch(void* const* d_in, const int* in_sizes, int n_in,
                              void* d_out, int out_size, void* d_ws, size_t ws_size,
                              hipStream_t stream)
{
    const float* image_feats = (const float*)d_in[0];
    const float* intr        = (const float*)d_in[1];
    const float* extr        = (const float*)d_in[2];
    const float* prev_bev    = (const float*)d_in[3];
    const float* bev_embed   = (const float*)d_in[4];
    const float* tsa_vw = (const float*)d_in[5];
    const float* tsa_vb = (const float*)d_in[6];
    const float* tsa_ow = (const float*)d_in[7];
    const float* tsa_ob = (const float*)d_in[8];
    const float* tsa_aw = (const float*)d_in[9];
    const float* tsa_ab = (const float*)d_in[10];
    const float* tsa_pw = (const float*)d_in[11];
    const float* tsa_pb = (const float*)d_in[12];
    const float* sca_vw = (const float*)d_in[13];
    const float* sca_vb = (const float*)d_in[14];
    const float* sca_ow = (const float*)d_in[15];
    const float* sca_ob = (const float*)d_in[16];
    const float* sca_aw = (const float*)d_in[17];
    const float* sca_ab = (const float*)d_in[18];
    const float* sca_pw = (const float*)d_in[19];
    const float* sca_pb = (const float*)d_in[20];
    const float* ffn_w1 = (const float*)d_in[21];
    const float* ffn_b1 = (const float*)d_in[22];
    const float* ffn_w2 = (const float*)d_in[23];
    const float* ffn_b2 = (const float*)d_in[24];
    const float* ln1_g  = (const float*)d_in[25];
    const float* ln1_b  = (const float*)d_in[26];
    const float* ln2_g  = (const float*)d_in[27];
    const float* ln2_b  = (const float*)d_in[28];
    const float* ln3_g  = (const float*)d_in[29];
    const float* ln3_b  = (const float*)d_in[30];

    // --- workspace layout (~246 MB of the 268 MB d_ws) ---
    char* wp = (char*)d_ws;
    auto alloc = [&](size_t bytes) -> void* {
        void* r = (void*)wp;
        wp += (bytes + 255) & ~(size_t)255;
        return r;
    };
    float* q      = (float*)alloc((size_t)NQ * CDIM * 4);
    bf16*  prevbf = (bf16*) alloc((size_t)NQ * CDIM * 2);
    bf16*  qb     = (bf16*) alloc((size_t)NQ * CDIM * 2);
    bf16*  attnA  = (bf16*) alloc((size_t)NQ * CDIM * 2);
    bf16*  vcur   = (bf16*) alloc((size_t)NQ * CDIM * 2);
    float* offlog = (float*)alloc((size_t)NQ * 128 * 4);
    float* refcam = (float*)alloc((size_t)NCAM * NQ * NPOINTS * 2 * 4);
    float* validb = (float*)alloc((size_t)NCAM * NQ * NPOINTS * 4);
    float* ego    = (float*)alloc(128 * 4);
    bf16*  featsT = (bf16*) alloc((size_t)NFEAT * CDIM * 2);   // union w/ hidden
    bf16*  pwT  = (bf16*)alloc((size_t)NLAYERS * 65536 * 2);
    bf16*  svwT = (bf16*)alloc((size_t)NLAYERS * 65536 * 2);
    bf16*  spwT = (bf16*)alloc((size_t)NLAYERS * 65536 * 2);
    bf16*  w1T  = (bf16*)alloc((size_t)NLAYERS * 131072 * 2);
    bf16*  w2T  = (bf16*)alloc((size_t)NLAYERS * 131072 * 2);
    bf16*  ptwT = (bf16*)alloc((size_t)NLAYERS * 384 * 256 * 2);  // tsa [vw|ow|aw|0]
    float* ptb  = (float*)alloc((size_t)NLAYERS * 384 * 4);
    bf16*  sowT = (bf16*)alloc((size_t)NLAYERS * 32768 * 2);
    float* sobF = (float*)alloc((size_t)NLAYERS * 128 * 4);
    bf16*  vprev6 = (bf16*)alloc((size_t)NLAYERS * NQ * CDIM * 2);   // 50.3 MB
    bf16*  vimg6  = (bf16*)alloc((size_t)NLAYERS * NFEAT * CDIM * 2); // 106.9 MB

    bf16* hidden = featsT;   // featsT consumed in prep; hidden used in loop

    dim3 blk32(32, 8);

    // --- prep ---
    init_q_kernel<<<(NQ * CDIM + 255) / 256, 256, 0, stream>>>(bev_embed, q, qb, NQ * CDIM);
    cvt_bf16_kernel<<<(NQ * CDIM + 255) / 256, 256, 0, stream>>>(prev_bev, prevbf, NQ * CDIM);
    invert4_kernel<<<1, 64, 0, stream>>>(extr, ego);
    refcam_kernel<<<(NCAM * NQ * NPOINTS + 255) / 256, 256, 0, stream>>>(ego, intr, refcam, validb);
    {
        dim3 g((HWF + 31) / 32, CDIM / 32, NCAM);
        feats_cvt_kernel<<<g, blk32, 0, stream>>>(image_feats, featsT);
    }
    wt_cvt_kernel<<<dim3(8, 8,  NLAYERS), blk32, 0, stream>>>(tsa_pw, pwT,  256, 256);
    wt_cvt_kernel<<<dim3(8, 8,  NLAYERS), blk32, 0, stream>>>(sca_vw, svwT, 256, 256);
    wt_cvt_kernel<<<dim3(8, 8,  NLAYERS), blk32, 0, stream>>>(sca_pw, spwT, 256, 256);
    wt_cvt_kernel<<<dim3(8, 16, NLAYERS), blk32, 0, stream>>>(ffn_w1, w1T, 256, 512);
    wt_cvt_kernel<<<dim3(16, 8, NLAYERS), blk32, 0, stream>>>(ffn_w2, w2T, 512, 256);
    pack_tsa_kernel<<<dim3(384, NLAYERS), 256, 0, stream>>>(
        tsa_vw, tsa_vb, tsa_ow, tsa_ob, tsa_aw, tsa_ab, ptwT, ptb);
    pack_offattn_kernel<<<dim3(128, NLAYERS), 256, 0, stream>>>(
        sca_ow, sca_ob, sca_aw, sca_ab, sowT, sobF);
    // all 6 layers of vimg (input-only)
    gemm_mfma<false><<<dim3(2, (NFEAT + 127) / 128, NLAYERS), 256, 0, stream>>>(
        featsT, svwT, sca_vb, vimg6, NFEAT, CDIM, CDIM,
        65536, 256, (size_t)NFEAT * CDIM);
    // all 6 layers of vprev (input-only; reuses ptwT rows 0..255 = vw^T)
    gemm_mfma<false><<<dim3(2, NQ / 128, NLAYERS), 256, 0, stream>>>(
        prevbf, ptwT, ptb, vprev6, NQ, CDIM, CDIM,
        98304, 384, (size_t)NQ * CDIM);

    for (int l = 0; l < NLAYERS; l++) {
        // ---- TSA: fused [vcur | offlog] GEMM from qb ----
        gemm_tsa<<<dim3(3, NQ / 128), 256, 0, stream>>>(
            qb, ptwT + (size_t)l * 98304, ptb + l * 384, vcur, offlog);
        tsa_sample_kernel<<<NQ / 8, 256, 0, stream>>>(
            vprev6 + (size_t)l * NQ * CDIM, vcur, offlog, attnA);
        gemm_ln<true><<<NQ / 64, 512, 0, stream>>>(
            attnA, pwT + (size_t)l * 65536, tsa_pb + l * CDIM,
            q, qb, ln1_g + l * CDIM, ln1_b + l * CDIM, CDIM,
            sowT + (size_t)l * 32768, sobF + l * 128, offlog);

        // ---- SCA ----
        sca_sample_kernel<<<NQ / 8, 256, 0, stream>>>(
            vimg6 + (size_t)l * NFEAT * CDIM, offlog, refcam, validb, attnA);
        gemm_ln<false><<<NQ / 64, 512, 0, stream>>>(
            attnA, spwT + (size_t)l * 65536, sca_pb + l * CDIM,
            q, qb, ln2_g + l * CDIM, ln2_b + l * CDIM, CDIM,
            nullptr, nullptr, nullptr);

        // ---- FFN ----
        gemm_mfma<true><<<dim3(4, NQ / 128, 1), 256, 0, stream>>>(
            qb, w1T + (size_t)l * 131072, ffn_b1 + l * 512, hidden, NQ, 512, CDIM, 0, 0, 0);
        gemm_ln<false><<<NQ / 64, 512, 0, stream>>>(
            hidden, w2T + (size_t)l * 131072, ffn_b2 + l * CDIM,
            q, qb, ln3_g + l * CDIM, ln3_b + l * CDIM, 512,
            nullptr, nullptr, nullptr);
    }

    {
        dim3 g(NQ / 32, CDIM / 32);
        out_transpose_kernel<<<g, blk32, 0, stream>>>(q, (float*)d_out);
    }
}